// Round 3
// baseline (7655.378 us; speedup 1.0000x reference)
//
#include <hip/hip_runtime.h>
#include <hip/hip_bf16.h>

// CirculantElmanCell: T=1024, B=16, D=2048
// out0: output [T,B,D] f32 ; out1: h [T+1,B,D] f32 (concatenated in d_out)

typedef __attribute__((ext_vector_type(8))) unsigned short us8;
typedef __attribute__((ext_vector_type(8))) __bf16 bf16x8;
typedef __attribute__((ext_vector_type(4))) float f32x4;

__device__ __forceinline__ int SIG(int i){ return i + (i >> 4); }  // LDS swizzle

__device__ __forceinline__ unsigned short f2bf(float f){
  unsigned int u = __float_as_uint(f);
  return (unsigned short)((u + 0x7FFFu + ((u >> 16) & 1u)) >> 16);
}

__device__ __forceinline__ void sincos2pi(float fr, float& sn, float& co){
#if __has_builtin(__builtin_amdgcn_sinf) && __has_builtin(__builtin_amdgcn_cosf)
  sn = __builtin_amdgcn_sinf(fr);   // v_sin_f32: input in revolutions
  co = __builtin_amdgcn_cosf(fr);
#else
  __sincosf(fr * 6.28318530717958647692f, &sn, &co);
#endif
}

__device__ __forceinline__ float2 cmul(float2 a, float2 b){
  return make_float2(a.x*b.x - a.y*b.y, a.x*b.y + a.y*b.x);
}
__device__ __forceinline__ float2 cadd(float2 a, float2 b){ return make_float2(a.x+b.x, a.y+b.y); }
__device__ __forceinline__ float2 csub(float2 a, float2 b){ return make_float2(a.x-b.x, a.y-b.y); }

__device__ __forceinline__ float tanh_fast(float x){
  float e = __expf(2.0f * x);
  return 1.0f - 2.0f / (e + 1.0f);
}

__device__ __forceinline__ float2 wn(int num, float dinv, int sgn){
  float sn, co; sincos2pi((float)num * dinv, sn, co);
  return make_float2(co, sgn > 0 ? sn : -sn);
}

template<int SGN>
__device__ __forceinline__ void dft4_full(const float2 a[4], float2 X[4]){
  float2 sA = cadd(a[0],a[2]), sB = csub(a[0],a[2]);
  float2 sC = cadd(a[1],a[3]), sD = csub(a[1],a[3]);
  float2 iD = make_float2(-(float)SGN*sD.y, (float)SGN*sD.x);
  X[0]=cadd(sA,sC); X[1]=cadd(sB,iD); X[2]=csub(sA,sC); X[3]=csub(sB,iD);
}

// Per-thread time-invariant constants (registers)
struct FSetup {
  float2 w16f[3], w16i[3];
  float2 twA[4], twB[4], twD[4], twE[4];
  float2 wmd[4];
  float2 lamA[4], lamB[4];
};

__device__ __forceinline__ void make_setup(FSetup& S, int tid, const float2* __restrict__ lam_g){
  const int sub = tid & 3, bf = tid >> 2;
  #pragma unroll
  for (int i = 0; i < 3; ++i){
    S.w16f[i] = wn(((i + 1) * sub) & 15, 1.0f/16.0f, -1);
    S.w16i[i] = make_float2(S.w16f[i].x, -S.w16f[i].y);
  }
  #pragma unroll
  for (int p2 = 0; p2 < 4; ++p2){
    S.twA[p2] = wn((bf * (sub + 4*p2)) & 1023, 1.0f/1024.0f, -1);
    S.twB[p2] = wn((16 * (bf >> 4) * (sub + 4*p2)) & 1023, 1.0f/1024.0f, -1);
    S.twD[p2] = wn((tid * p2) & 1023, 1.0f/1024.0f, +1);
    S.twE[p2] = wn((4 * (bf >> 2) * (sub + 4*p2)) & 1023, 1.0f/1024.0f, +1);
  }
  #pragma unroll
  for (int q = 0; q < 4; ++q){
    int k = tid + 256 * q;
    S.wmd[q]  = wn(k & 2047, 1.0f/2048.0f, -1);
    S.lamA[q] = lam_g[k];
    S.lamB[q] = lam_g[k + 1024];
  }
}

// radix-16 butterfly compute from 16 loaded inputs; X[p2] = out(p=sub+4*p2), twiddle applied
template<int SGN>
__device__ __forceinline__ void r16_core(const float2 in[16], int sub,
                                         const float2* w16, const float2* tw, float2 X[4]){
  float2 Y[4];
  #pragma unroll
  for (int q1 = 0; q1 < 4; ++q1){
    float2 a0=in[q1], a1=in[q1+4], a2=in[q1+8], a3=in[q1+12];
    float2 sA=cadd(a0,a2), sB=csub(a0,a2), sC=cadd(a1,a3), sD=csub(a1,a3);
    float2 iD=make_float2(-(float)SGN*sD.y, (float)SGN*sD.x);
    float2 u = (sub & 1) ? sB : sA;
    float2 v = (sub & 1) ? iD : sC;
    Y[q1] = (sub & 2) ? csub(u, v) : cadd(u, v);
  }
  Y[1]=cmul(Y[1],w16[0]); Y[2]=cmul(Y[2],w16[1]); Y[3]=cmul(Y[3],w16[2]);
  float2 sA=cadd(Y[0],Y[2]), sB=csub(Y[0],Y[2]), sC=cadd(Y[1],Y[3]), sD=csub(Y[1],Y[3]);
  float2 iD=make_float2(-(float)SGN*sD.y, (float)SGN*sD.x);
  X[0]=cmul(cadd(sA,sC),tw[0]); X[1]=cmul(cadd(sB,iD),tw[1]);
  X[2]=cmul(csub(sA,sC),tw[2]); X[3]=cmul(csub(sB,iD),tw[3]);
}

// dual-row radix-16 Stockham stage: both rows loaded first, then computed.
template<int L, int M, int SGN>
__device__ __forceinline__ void r16_dual(const float2* s0, float2* d0,
                                         const float2* s1, float2* d1,
                                         int bf, int sub, const float2* w16, const float2* tw){
  const int j = bf / M, k = bf - j * M;
  const int base = k + M * j;
  float2 in0[16], in1[16];
  #pragma unroll
  for (int q = 0; q < 16; ++q) in0[q] = s0[SIG(base + 64 * q)];
  #pragma unroll
  for (int q = 0; q < 16; ++q) in1[q] = s1[SIG(base + 64 * q)];
  const int obase = k + M * (16 * j + sub);
  float2 X0[4]; r16_core<SGN>(in0, sub, w16, tw, X0);
  #pragma unroll
  for (int p2 = 0; p2 < 4; ++p2) d0[SIG(obase + 4 * M * p2)] = X0[p2];
  float2 X1[4]; r16_core<SGN>(in1, sub, w16, tw, X1);
  #pragma unroll
  for (int p2 = 0; p2 < 4; ++p2) d1[SIG(obase + 4 * M * p2)] = X1[p2];
}

// single-row version (circx)
template<int L, int M, int SGN>
__device__ __forceinline__ void r16(const float2* src, float2* dst, int bf, int sub,
                                    const float2* w16, const float2* tw){
  const int j = bf / M, k = bf - j * M;
  const int base = k + M * j;
  float2 in[16];
  #pragma unroll
  for (int q = 0; q < 16; ++q) in[q] = src[SIG(base + 64 * q)];
  float2 X[4]; r16_core<SGN>(in, sub, w16, tw, X);
  const int obase = k + M * (16 * j + sub);
  #pragma unroll
  for (int p2 = 0; p2 < 4; ++p2) dst[SIG(obase + 4 * M * p2)] = X[p2];
}

// final inverse stage (L=1,M=64,SGN=+1): outputs X[p2] at element bf + 64*sub + 256*p2
__device__ __forceinline__ void r16_final(const float2* src, int bf, int sub,
                                          const float2* w16, float2 X[4]){
  float2 in[16];
  #pragma unroll
  for (int q = 0; q < 16; ++q) in[q] = src[SIG(bf + 64 * q)];
  float2 Y[4];
  #pragma unroll
  for (int q1 = 0; q1 < 4; ++q1){
    float2 a0=in[q1], a1=in[q1+4], a2=in[q1+8], a3=in[q1+12];
    float2 sA=cadd(a0,a2), sB=csub(a0,a2), sC=cadd(a1,a3), sD=csub(a1,a3);
    float2 iD=make_float2(-sD.y, sD.x);
    float2 u = (sub & 1) ? sB : sA;
    float2 v = (sub & 1) ? iD : sC;
    Y[q1] = (sub & 2) ? csub(u, v) : cadd(u, v);
  }
  Y[1]=cmul(Y[1],w16[0]); Y[2]=cmul(Y[2],w16[1]); Y[3]=cmul(Y[3],w16[2]);
  float2 sA=cadd(Y[0],Y[2]), sB=csub(Y[0],Y[2]), sC=cadd(Y[1],Y[3]), sD=csub(Y[1],Y[3]);
  float2 iD=make_float2(-sD.y, sD.x);
  X[0]=cadd(sA,sC); X[1]=cadd(sB,iD); X[2]=csub(sA,sC); X[3]=csub(sB,iD);
}

// phase-D core: fwd r4 (butterflies t and 256-t) + Hermitian*lam + inv r4 stage1, twD applied
__device__ __forceinline__ void phaseD_core(const float2 a0[4], const float2 b0[4],
                                            int tid, const FSetup& S, float2 Xo[4]){
  float2 Z1[4], Z2[4];
  dft4_full<-1>(a0, Z1);
  dft4_full<-1>(b0, Z2);
  float2 Wv[4];
  #pragma unroll
  for (int q = 0; q < 4; ++q){
    float2 zk = Z1[q];
    float2 zp = Z2[3 - q];
    if (tid == 0) zp = Z2[(4 - q) & 3];
    float2 E = make_float2(0.5f*(zk.x+zp.x),  0.5f*(zk.y-zp.y));
    float2 O = make_float2(0.5f*(zk.y+zp.y), -0.5f*(zk.x-zp.x));
    float2 w = S.wmd[q];
    float2 wO = cmul(w, O);
    float2 Hk  = cadd(E, wO), Hk2 = csub(E, wO);
    float2 Yk  = cmul(Hk,  S.lamA[q]);
    float2 Yk2 = cmul(Hk2, S.lamB[q]);
    float2 Sm = cadd(Yk, Yk2), Dd = csub(Yk, Yk2);
    float2 cw = make_float2(w.x, -w.y);
    float2 cd = cmul(cw, Dd);
    Wv[q] = make_float2(Sm.x - cd.y, Sm.y + cd.x);
  }
  float2 X[4]; dft4_full<1>(Wv, X);
  #pragma unroll
  for (int p = 0; p < 4; ++p) Xo[p] = cmul(X[p], S.twD[p]);
}

__device__ __forceinline__ void phaseD_dual(const float2* s0, float2* d0,
                                            const float2* s1, float2* d1,
                                            int tid, const FSetup& S){
  const int k2 = (256 - tid) & 255;
  float2 a0[4], b0[4], a1[4], b1[4];
  #pragma unroll
  for (int q = 0; q < 4; ++q){
    a0[q] = s0[SIG(tid + 256*q)];
    b0[q] = s0[SIG(k2  + 256*q)];
  }
  #pragma unroll
  for (int q = 0; q < 4; ++q){
    a1[q] = s1[SIG(tid + 256*q)];
    b1[q] = s1[SIG(k2  + 256*q)];
  }
  float2 X0[4]; phaseD_core(a0, b0, tid, S, X0);
  #pragma unroll
  for (int p = 0; p < 4; ++p) d0[SIG(4*tid + p)] = X0[p];
  float2 X1[4]; phaseD_core(a1, b1, tid, S, X1);
  #pragma unroll
  for (int p = 0; p < 4; ++p) d1[SIG(4*tid + p)] = X1[p];
}

__device__ __forceinline__ void phaseD(const float2* src, float2* dst, int tid, const FSetup& S){
  const int k2 = (256 - tid) & 255;
  float2 a0[4], b0[4];
  #pragma unroll
  for (int q = 0; q < 4; ++q){
    a0[q] = src[SIG(tid + 256*q)];
    b0[q] = src[SIG(k2  + 256*q)];
  }
  float2 X[4]; phaseD_core(a0, b0, tid, S, X);
  #pragma unroll
  for (int p = 0; p < 4; ++p) dst[SIG(4*tid + p)] = X[p];
}

// single-row 4 phases (circx)
__device__ __forceinline__ void fft5_phases(float2* hz, float2* bA, float2* bB,
                                            int tid, const FSetup& S){
  const int bf = tid >> 2, sub = tid & 3;
  r16<64,  1, -1>(hz, bA, bf, sub, S.w16f, S.twA); __syncthreads();
  r16< 4, 16, -1>(bA, bB, bf, sub, S.w16f, S.twB); __syncthreads();
  phaseD(bB, bA, tid, S);                          __syncthreads();
  r16<16,  4,  1>(bA, bB, bf, sub, S.w16i, S.twE); __syncthreads();
}

// ---------------- f32 -> bf16 bulk convert ----------------
__global__ __launch_bounds__(256) void cvt_bf16(const float* __restrict__ in,
                                                unsigned short* __restrict__ out, int n8){
  int i = blockIdx.x * 256 + threadIdx.x;
  if (i >= n8) return;
  float4 a = ((const float4*)in)[2 * i];
  float4 b = ((const float4*)in)[2 * i + 1];
  us8 r;
  r[0] = f2bf(a.x); r[1] = f2bf(a.y); r[2] = f2bf(a.z); r[3] = f2bf(a.w);
  r[4] = f2bf(b.x); r[5] = f2bf(b.y); r[6] = f2bf(b.z); r[7] = f2bf(b.w);
  ((us8*)out)[i] = r;
}

// ---------------- lam[k] = fft(c)[k] / 2048 ----------------
__global__ __launch_bounds__(256) void dft_c(const float* __restrict__ c, float2* __restrict__ lam){
  __shared__ float cs[2048];
  int tid = threadIdx.x;
  for (int i = tid; i < 2048; i += 256) cs[i] = c[i];
  __syncthreads();
  int k = blockIdx.x * 256 + tid;
  float sr = 0.f, si = 0.f;
  for (int j = 0; j < 2048; ++j){
    int ph = (j * k) & 2047;
    float sn, co; sincos2pi((float)ph * (1.0f / 2048.0f), sn, co);
    float cv = cs[j];
    sr = __fmaf_rn(cv,  co, sr);
    si = __fmaf_rn(-cv, sn, si);
  }
  lam[k] = make_float2(sr * (1.0f / 2048.0f), si * (1.0f / 2048.0f));
}

// ---------------- circ_x: pre[row] = ifft(lamx*fft(x_row)) + b ----------------
__global__ __launch_bounds__(256, 2) void circx(const float* __restrict__ x,
                                                const float* __restrict__ bias,
                                                const float2* __restrict__ lam_g,
                                                float* __restrict__ pre){
  __shared__ float2 hz[1088], bA[1088], bB[1088];
  const int tid = threadIdx.x;
  FSetup S; make_setup(S, tid, lam_g);
  const int bf = tid >> 2, sub = tid & 3;
  const int i0 = bf + 64 * sub;
  float2 bv[4];
  #pragma unroll
  for (int p2 = 0; p2 < 4; ++p2) bv[p2] = ((const float2*)bias)[i0 + 256*p2];
  for (int r = 0; r < 8; ++r){
    const size_t row = (size_t)blockIdx.x * 8 + r;
    const float2* xr = (const float2*)(x + row * 2048);
    for (int i = tid; i < 1024; i += 256) hz[SIG(i)] = xr[i];
    __syncthreads();
    fft5_phases(hz, bA, bB, tid, S);
    float2 X[4]; r16_final(bB, bf, sub, S.w16i, X);
    float2* prow = (float2*)(pre + row * 2048);
    #pragma unroll
    for (int p2 = 0; p2 < 4; ++p2){
      int n = i0 + 256*p2;
      prow[n] = make_float2(X[p2].x + bv[p2].x, X[p2].y + bv[p2].y);
    }
    __syncthreads();
  }
}

// ---------------- gate GEMM: g = silu(xb @ Wb^T + bg) -> h rows 1..T ----------------
__global__ __launch_bounds__(256) void gemm_gate(const unsigned short* __restrict__ A,
                                                 const unsigned short* __restrict__ B,
                                                 const float* __restrict__ bg,
                                                 float* __restrict__ houtp){
  __shared__ unsigned short As[128 * 32];
  __shared__ unsigned short Bs[128 * 32];
  const int tid  = threadIdx.x;
  const int lane = tid & 63;
  const int wave = tid >> 6;
  const int wr = wave >> 1, wc = wave & 1;
  const int m0 = blockIdx.x * 128, n0 = blockIdx.y * 128;

  const int srow = tid >> 1;
  const int scol = (tid & 1) << 4;
  const unsigned short* ga = A + (size_t)(m0 + srow) * 2048 + scol;
  const unsigned short* gb = B + (size_t)(n0 + srow) * 2048 + scol;
  unsigned short* la = As + srow * 32 + scol;
  unsigned short* lb = Bs + srow * 32 + scol;

  f32x4 acc[4][4];
  #pragma unroll
  for (int m = 0; m < 4; ++m)
    #pragma unroll
    for (int n = 0; n < 4; ++n)
      acc[m][n] = f32x4{0.f, 0.f, 0.f, 0.f};

  const int arow = wr * 64 + (lane & 15);
  const int brow = wc * 64 + (lane & 15);
  const int koff = (lane >> 4) * 8;

  for (int ks = 0; ks < 64; ++ks){
    const int k0 = ks * 32;
    us8 va0 = *(const us8*)(ga + k0);
    us8 va1 = *(const us8*)(ga + k0 + 8);
    us8 vb0 = *(const us8*)(gb + k0);
    us8 vb1 = *(const us8*)(gb + k0 + 8);
    __syncthreads();
    *(us8*)(la)     = va0; *(us8*)(la + 8) = va1;
    *(us8*)(lb)     = vb0; *(us8*)(lb + 8) = vb1;
    __syncthreads();
    bf16x8 av[4], bv[4];
    #pragma unroll
    for (int m = 0; m < 4; ++m) av[m] = *(const bf16x8*)(As + (arow + m * 16) * 32 + koff);
    #pragma unroll
    for (int n = 0; n < 4; ++n) bv[n] = *(const bf16x8*)(Bs + (brow + n * 16) * 32 + koff);
    #pragma unroll
    for (int m = 0; m < 4; ++m)
      #pragma unroll
      for (int n = 0; n < 4; ++n)
        acc[m][n] = __builtin_amdgcn_mfma_f32_16x16x32_bf16(av[m], bv[n], acc[m][n], 0, 0, 0);
  }
  #pragma unroll
  for (int n = 0; n < 4; ++n){
    const int ng = n0 + wc * 64 + n * 16 + (lane & 15);
    const float bgv = bg[ng];
    #pragma unroll
    for (int m = 0; m < 4; ++m){
      const int mbase = m0 + wr * 64 + m * 16 + (lane >> 4) * 4;
      #pragma unroll
      for (int r = 0; r < 4; ++r){
        float v = acc[m][n][r] + bgv;
        float s = v / (1.0f + __expf(-v));
        houtp[(size_t)(mbase + r + 16) * 2048 + ng] = s;
      }
    }
  }
}

// ---------------- sequential recurrence: 1 block per TWO batch rows ----------------
__global__ __launch_bounds__(256, 1) void recur2(const float* __restrict__ h0,
                                                 const float2* __restrict__ lam_g,
                                                 float* __restrict__ outp,    // pre on entry, out on exit
                                                 float* __restrict__ houtp){  // rows 1..T: g -> h
  __shared__ float2 hz0[1088], bA0[1088], bB0[1088];
  __shared__ float2 hz1[1088], bA1[1088], bB1[1088];
  const int tid = threadIdx.x;
  const int r0  = blockIdx.x * 2;
  const int r1  = r0 + 1;
  FSetup S; make_setup(S, tid, lam_g);
  {
    const float2* h0a = (const float2*)(h0 + (size_t)r0 * 2048);
    const float2* h0b = (const float2*)(h0 + (size_t)r1 * 2048);
    float2* hra = (float2*)(houtp + (size_t)r0 * 2048);
    float2* hrb = (float2*)(houtp + (size_t)r1 * 2048);
    for (int i = tid; i < 1024; i += 256){
      float2 va = h0a[i]; hz0[SIG(i)] = va; hra[i] = va;
      float2 vb = h0b[i]; hz1[SIG(i)] = vb; hrb[i] = vb;
    }
  }
  __syncthreads();
  const int bf = tid >> 2, sub = tid & 3;
  const int i0 = bf + 64 * sub;
  #pragma unroll 1
  for (int t = 0; t < 1024; ++t){
    float2* orow0 = (float2*)(outp  + ((size_t)t * 16 + r0) * 2048);
    float2* hrow0 = (float2*)(houtp + ((size_t)(t + 1) * 16 + r0) * 2048);
    float2* orow1 = (float2*)(outp  + ((size_t)t * 16 + r1) * 2048);
    float2* hrow1 = (float2*)(houtp + ((size_t)(t + 1) * 16 + r1) * 2048);
    float2 pr0[4], gv0[4], pr1[4], gv1[4];
    #pragma unroll
    for (int p2 = 0; p2 < 4; ++p2){
      pr0[p2] = orow0[i0 + 256*p2]; gv0[p2] = hrow0[i0 + 256*p2];
      pr1[p2] = orow1[i0 + 256*p2]; gv1[p2] = hrow1[i0 + 256*p2];
    }
    r16_dual<64,  1, -1>(hz0, bA0, hz1, bA1, bf, sub, S.w16f, S.twA); __syncthreads();
    r16_dual< 4, 16, -1>(bA0, bB0, bA1, bB1, bf, sub, S.w16f, S.twB); __syncthreads();
    phaseD_dual(bB0, bA0, bB1, bA1, tid, S);                          __syncthreads();
    r16_dual<16,  4,  1>(bA0, bB0, bA1, bB1, bf, sub, S.w16i, S.twE); __syncthreads();
    float2 X0[4]; r16_final(bB0, bf, sub, S.w16i, X0);
    float2 X1[4]; r16_final(bB1, bf, sub, S.w16i, X1);
    #pragma unroll
    for (int p2 = 0; p2 < 4; ++p2){
      int n = i0 + 256*p2;
      float a0 = tanh_fast(X0[p2].x + pr0[p2].x);
      float a1 = tanh_fast(X0[p2].y + pr0[p2].y);
      float2 hv0 = make_float2(a0, a1);
      hz0[SIG(n)] = hv0;
      hrow0[n] = hv0;
      orow0[n] = make_float2(a0 * gv0[p2].x, a1 * gv0[p2].y);
      float b0 = tanh_fast(X1[p2].x + pr1[p2].x);
      float b1 = tanh_fast(X1[p2].y + pr1[p2].y);
      float2 hv1 = make_float2(b0, b1);
      hz1[SIG(n)] = hv1;
      hrow1[n] = hv1;
      orow1[n] = make_float2(b0 * gv1[p2].x, b1 * gv1[p2].y);
    }
    __syncthreads();
  }
}

extern "C" void kernel_launch(void* const* d_in, const int* in_sizes, int n_in,
                              void* d_out, int out_size, void* d_ws, size_t ws_size,
                              hipStream_t stream){
  const float* x  = (const float*)d_in[0];
  const float* h0 = (const float*)d_in[1];
  const float* ch = (const float*)d_in[2];
  const float* cx = (const float*)d_in[3];
  const float* Wg = (const float*)d_in[4];
  const float* bb = (const float*)d_in[5];
  const float* bg = (const float*)d_in[6];
  float* outp  = (float*)d_out;                        // [T,B,D]
  float* houtp = outp + (size_t)1024 * 16 * 2048;      // [T+1,B,D]

  char* w = (char*)d_ws;
  unsigned short* xb = (unsigned short*)w; w += (size_t)16384 * 2048 * 2;
  unsigned short* Wb = (unsigned short*)w; w += (size_t)2048 * 2048 * 2;
  float2* lamh = (float2*)w; w += 2048 * sizeof(float2);
  float2* lamx = (float2*)w; w += 2048 * sizeof(float2);

  cvt_bf16 <<<dim3(16384), dim3(256), 0, stream>>>(x,  xb, 16384 * 2048 / 8);
  cvt_bf16 <<<dim3(2048),  dim3(256), 0, stream>>>(Wg, Wb,  2048 * 2048 / 8);
  dft_c    <<<dim3(8),     dim3(256), 0, stream>>>(ch, lamh);
  dft_c    <<<dim3(8),     dim3(256), 0, stream>>>(cx, lamx);
  circx    <<<dim3(2048),  dim3(256), 0, stream>>>(x, bb, lamx, outp);       // pre -> outp
  gemm_gate<<<dim3(128,16),dim3(256), 0, stream>>>(xb, Wb, bg, houtp);       // g -> h rows 1..T
  recur2   <<<dim3(8),     dim3(256), 0, stream>>>(h0, lamh, outp, houtp);
}

// Round 4
// 3443.094 us; speedup vs baseline: 2.2234x; 2.2234x over previous
//
#include <hip/hip_runtime.h>
#include <hip/hip_bf16.h>

// CirculantElmanCell: T=1024, B=16, D=2048
// out0: output [T,B,D] f32 ; out1: h [T+1,B,D] f32 (concatenated in d_out)

typedef __attribute__((ext_vector_type(8))) unsigned short us8;
typedef __attribute__((ext_vector_type(8))) __bf16 bf16x8;
typedef __attribute__((ext_vector_type(4))) float f32x4;

__device__ __forceinline__ int SIG(int i){ return i + (i >> 4); }            // old swizzle (circx)
__device__ __forceinline__ int S2(int i){ return i + (i >> 4) + (i >> 6); }  // new swizzle (recur)

// LDS-only barrier: no vmcnt drain (global loads/stores stay in flight)
#define LDSBAR() do { \
  asm volatile("s_waitcnt lgkmcnt(0)\n\ts_barrier" ::: "memory"); \
  __builtin_amdgcn_sched_barrier(0); \
} while (0)

__device__ __forceinline__ unsigned short f2bf(float f){
  unsigned int u = __float_as_uint(f);
  return (unsigned short)((u + 0x7FFFu + ((u >> 16) & 1u)) >> 16);
}

__device__ __forceinline__ void sincos2pi(float fr, float& sn, float& co){
#if __has_builtin(__builtin_amdgcn_sinf) && __has_builtin(__builtin_amdgcn_cosf)
  sn = __builtin_amdgcn_sinf(fr);   // v_sin_f32: revolutions
  co = __builtin_amdgcn_cosf(fr);
#else
  __sincosf(fr * 6.28318530717958647692f, &sn, &co);
#endif
}

__device__ __forceinline__ float2 cmul(float2 a, float2 b){
  return make_float2(a.x*b.x - a.y*b.y, a.x*b.y + a.y*b.x);
}
__device__ __forceinline__ float2 cadd(float2 a, float2 b){ return make_float2(a.x+b.x, a.y+b.y); }
__device__ __forceinline__ float2 csub(float2 a, float2 b){ return make_float2(a.x-b.x, a.y-b.y); }

__device__ __forceinline__ float tanh_fast(float x){
  float e = __expf(2.0f * x);
  return 1.0f - 2.0f / (e + 1.0f);
}

__device__ __forceinline__ float2 wn(int num, float dinv, int sgn){
  float sn, co; sincos2pi((float)num * dinv, sn, co);
  return make_float2(co, sgn > 0 ? sn : -sn);
}

template<int SGN>
__device__ __forceinline__ void dft4_full(const float2 a[4], float2 X[4]){
  float2 sA = cadd(a[0],a[2]), sB = csub(a[0],a[2]);
  float2 sC = cadd(a[1],a[3]), sD = csub(a[1],a[3]);
  float2 iD = make_float2(-(float)SGN*sD.y, (float)SGN*sD.x);
  X[0]=cadd(sA,sC); X[1]=cadd(sB,iD); X[2]=csub(sA,sC); X[3]=csub(sB,iD);
}

// ---------------- DPP quad shuffles (VALU pipe) ----------------
template<int CTRL>
__device__ __forceinline__ float2 dpp2(float2 v){
  float2 r;
  r.x = __int_as_float(__builtin_amdgcn_mov_dpp(__float_as_int(v.x), CTRL, 0xF, 0xF, true));
  r.y = __int_as_float(__builtin_amdgcn_mov_dpp(__float_as_int(v.y), CTRL, 0xF, 0xF, true));
  return r;
}
#define DPP_XOR1 0xB1  // quad_perm [1,0,3,2]
#define DPP_XOR2 0x4E  // quad_perm [2,3,0,1]

// =====================================================================
// recur_q: quad-distributed radix-16 Stockham, 256 threads, 4 pts/thread
// =====================================================================

// One radix-16 stage. Q=tid>>2, c=tid&3. Lane holds outputs p = p1 + 4*p2,
// p2 = bitrev2(c), p1 = register index. cornT = W16^{SGN*c*p1} (p1=1..3);
// stw[p1] = W1024^{SGN*j*M*(p1+4*p2)}.
template<int M, int SGN>
__device__ __forceinline__ void qr16_core(const float2* src, int Q, int c,
                                          float sg1, float sg2,
                                          const float2* cornT, float2 T[4]){
  const int j = Q / M, k = Q - j*M;
  const int base = k + M*j + 64*c;
  float2 i0 = src[S2(base)];
  float2 i1 = src[S2(base + 256)];
  float2 i2 = src[S2(base + 512)];
  float2 i3 = src[S2(base + 768)];
  // in-thread DFT4 over register digit (q2), kernel (SGN*i)^{p1*r}
  float2 e = cadd(i0,i2), f = csub(i0,i2);
  float2 g = cadd(i1,i3), h = csub(i1,i3);
  float2 ih = (SGN>0)? make_float2(-h.y, h.x) : make_float2(h.y, -h.x);
  T[0]=cadd(e,g); T[1]=cadd(f,ih); T[2]=csub(e,g); T[3]=csub(f,ih);
  // corner twiddle W16^{SGN*c*p1}
  T[1]=cmul(T[1],cornT[0]); T[2]=cmul(T[2],cornT[1]); T[3]=cmul(T[3],cornT[2]);
  // cross-quad DFT4 over c: inner exchange (xor2), +/-i twiddle at c==3, outer (xor1)
  #pragma unroll
  for (int p1=0;p1<4;++p1){
    float2 t = dpp2<DPP_XOR2>(T[p1]);
    T[p1] = make_float2(fmaf(sg2, T[p1].x, t.x), fmaf(sg2, T[p1].y, t.y));
  }
  if (c == 3){
    #pragma unroll
    for (int p1=0;p1<4;++p1)
      T[p1] = (SGN>0)? make_float2(-T[p1].y, T[p1].x) : make_float2(T[p1].y, -T[p1].x);
  }
  #pragma unroll
  for (int p1=0;p1<4;++p1){
    float2 u = dpp2<DPP_XOR1>(T[p1]);
    T[p1] = make_float2(fmaf(sg1, T[p1].x, u.x), fmaf(sg1, T[p1].y, u.y));
  }
}

template<int M, int SGN>
__device__ __forceinline__ void qr16(const float2* src, float2* dst, int Q, int c, int p2,
                                     float sg1, float sg2,
                                     const float2* cornT, const float2* stw){
  float2 T[4];
  qr16_core<M,SGN>(src, Q, c, sg1, sg2, cornT, T);
  const int j = Q / M, k = Q - j*M;
  const int wb = k + M*(16*j + 4*p2);
  dst[S2(wb)]       = cmul(T[0], stw[0]);
  dst[S2(wb + M)]   = cmul(T[1], stw[1]);
  dst[S2(wb + 2*M)] = cmul(T[2], stw[2]);
  dst[S2(wb + 3*M)] = cmul(T[3], stw[3]);
}

// mid phase (fwd r4 + Hermitian*lam + inv r4), in-thread, ported from passing R2 code
__device__ __forceinline__ void phaseD2(const float2* src, float2* dst, int tid,
                                        const float2* wmd, const float2* lamA,
                                        const float2* lamB, const float2* twD){
  const int k2 = (256 - tid) & 255;
  float2 a0[4], b0[4];
  #pragma unroll
  for (int q=0;q<4;++q){ a0[q] = src[S2(tid + 256*q)]; b0[q] = src[S2(k2 + 256*q)]; }
  float2 Z1[4], Z2[4];
  dft4_full<-1>(a0, Z1);
  dft4_full<-1>(b0, Z2);
  float2 Wv[4];
  #pragma unroll
  for (int q=0;q<4;++q){
    float2 zk = Z1[q];
    float2 zp = Z2[3-q];
    if (tid == 0) zp = Z2[(4-q)&3];
    float2 E = make_float2(0.5f*(zk.x+zp.x),  0.5f*(zk.y-zp.y));
    float2 O = make_float2(0.5f*(zk.y+zp.y), -0.5f*(zk.x-zp.x));
    float2 w = wmd[q];
    float2 wO = cmul(w, O);
    float2 Hk  = cadd(E, wO), Hk2 = csub(E, wO);
    float2 Yk  = cmul(Hk,  lamA[q]);
    float2 Yk2 = cmul(Hk2, lamB[q]);
    float2 Sm = cadd(Yk, Yk2), Dd = csub(Yk, Yk2);
    float2 cw = make_float2(w.x, -w.y);
    float2 cd = cmul(cw, Dd);
    Wv[q] = make_float2(Sm.x - cd.y, Sm.y + cd.x);
  }
  float2 X[4]; dft4_full<1>(Wv, X);
  #pragma unroll
  for (int p=0;p<4;++p) dst[S2(4*tid+p)] = cmul(X[p], twD[p]);
}

__global__ __launch_bounds__(256, 1) void recur_q(const float* __restrict__ h0,
                                                  const float2* __restrict__ lam_g,
                                                  float* __restrict__ outp,    // pre in, out out
                                                  float* __restrict__ houtp){  // rows 1..T: g -> h
  __shared__ float2 hz[1104], bA[1104], bB[1104];
  const int tid = threadIdx.x;
  const int b   = blockIdx.x;
  const int Q = tid >> 2, c = tid & 3;
  const int p2 = ((c & 1) << 1) | ((c >> 1) & 1);       // bitrev2(c)
  const float sg1 = (c & 1) ? -1.f : 1.f;
  const float sg2 = (c & 2) ? -1.f : 1.f;
  // per-thread constant tables
  float2 cornF[3], cornI[3], twA[4], twB[4], twE[4], twD[4], wmd[4], lamA[4], lamB[4];
  #pragma unroll
  for (int p1=1;p1<4;++p1){
    cornF[p1-1] = wn((c*p1) & 15, 1.f/16.f, -1);
    cornI[p1-1] = make_float2(cornF[p1-1].x, -cornF[p1-1].y);
  }
  #pragma unroll
  for (int p1=0;p1<4;++p1){
    const int p = p1 + 4*p2;
    twA[p1] = wn((Q*p) & 1023, 1.f/1024.f, -1);               // A: j=Q, M=1
    twB[p1] = wn((16*(Q>>4)*p) & 1023, 1.f/1024.f, -1);       // B: j=Q>>4, M=16
    twE[p1] = wn((4*(Q>>2)*p) & 1023, 1.f/1024.f, +1);        // E: j=Q>>2, M=4
    twD[p1] = wn((tid*p1) & 1023, 1.f/1024.f, +1);            // invD: j=tid, M=1
    const int k = tid + 256*p1;
    wmd[p1]  = wn(k & 2047, 1.f/2048.f, -1);
    lamA[p1] = lam_g[k];
    lamB[p1] = lam_g[k + 1024];
  }
  const int nb = Q + 256*p2;  // this lane's output points: n = nb + 64*p1
  // init: h0 -> hz (swizzled) and h row 0 (linear)
  {
    const float2* h02 = (const float2*)(h0 + (size_t)b * 2048);
    float2* hrow0 = (float2*)(houtp + (size_t)b * 2048);
    for (int i = tid; i < 1024; i += 256){ float2 v = h02[i]; hz[S2(i)] = v; hrow0[i] = v; }
  }
  __syncthreads();
  #pragma unroll 1
  for (int t = 0; t < 1024; ++t){
    float* orow = outp  + ((size_t)t * 16 + b) * 2048;
    float* hrow = houtp + ((size_t)(t + 1) * 16 + b) * 2048;
    float2 pr[4], gv[4];
    #pragma unroll
    for (int p1=0;p1<4;++p1){
      pr[p1] = *(const float2*)(orow + 2*(nb + 64*p1));
      gv[p1] = *(const float2*)(hrow + 2*(nb + 64*p1));
    }
    qr16<1,  -1>(hz, bA, Q, c, p2, sg1, sg2, cornF, twA); LDSBAR();
    qr16<16, -1>(bA, bB, Q, c, p2, sg1, sg2, cornF, twB); LDSBAR();
    phaseD2(bB, bA, tid, wmd, lamA, lamB, twD);           LDSBAR();
    qr16<4,   1>(bA, bB, Q, c, p2, sg1, sg2, cornI, twE); LDSBAR();
    // phase F: inv final (L=1, M=64), no stage twiddle; outputs n = nb + 64*p1
    float2 T[4];
    qr16_core<64, 1>(bB, Q, c, sg1, sg2, cornI, T);
    #pragma unroll
    for (int p1=0;p1<4;++p1){
      const int n = nb + 64*p1;
      float hx = tanh_fast(T[p1].x + pr[p1].x);
      float hy = tanh_fast(T[p1].y + pr[p1].y);
      float ox = hx * gv[p1].x, oy = hy * gv[p1].y;
      // tie h to gv: hrow store (same addr as gv load) must not pass the load
      asm volatile("" : "+v"(hx), "+v"(hy) : "v"(gv[p1].x), "v"(gv[p1].y));
      float2 hv = make_float2(hx, hy);
      hz[S2(n)] = hv;
      *(float2*)(hrow + 2*n) = hv;
      *(float2*)(orow + 2*n) = make_float2(ox, oy);
    }
    LDSBAR();
  }
}

// =====================================================================
// circx path (unchanged from passing R2 code, 256-thread r16 in LDS)
// =====================================================================
struct FSetup {
  float2 w16f[3], w16i[3];
  float2 twA[4], twB[4], twD[4], twE[4];
  float2 wmd[4];
  float2 lamA[4], lamB[4];
};

__device__ __forceinline__ void make_setup(FSetup& S, int tid, const float2* __restrict__ lam_g){
  const int sub = tid & 3, bf = tid >> 2;
  #pragma unroll
  for (int i = 0; i < 3; ++i){
    S.w16f[i] = wn(((i + 1) * sub) & 15, 1.0f/16.0f, -1);
    S.w16i[i] = make_float2(S.w16f[i].x, -S.w16f[i].y);
  }
  #pragma unroll
  for (int p2 = 0; p2 < 4; ++p2){
    S.twA[p2] = wn((bf * (sub + 4*p2)) & 1023, 1.0f/1024.0f, -1);
    S.twB[p2] = wn((16 * (bf >> 4) * (sub + 4*p2)) & 1023, 1.0f/1024.0f, -1);
    S.twD[p2] = wn((tid * p2) & 1023, 1.0f/1024.0f, +1);
    S.twE[p2] = wn((4 * (bf >> 2) * (sub + 4*p2)) & 1023, 1.0f/1024.0f, +1);
  }
  #pragma unroll
  for (int q = 0; q < 4; ++q){
    int k = tid + 256 * q;
    S.wmd[q]  = wn(k & 2047, 1.0f/2048.0f, -1);
    S.lamA[q] = lam_g[k];
    S.lamB[q] = lam_g[k + 1024];
  }
}

template<int SGN>
__device__ __forceinline__ void r16_core(const float2 in[16], int sub,
                                         const float2* w16, const float2* tw, float2 X[4]){
  float2 Y[4];
  #pragma unroll
  for (int q1 = 0; q1 < 4; ++q1){
    float2 a0=in[q1], a1=in[q1+4], a2=in[q1+8], a3=in[q1+12];
    float2 sA=cadd(a0,a2), sB=csub(a0,a2), sC=cadd(a1,a3), sD=csub(a1,a3);
    float2 iD=make_float2(-(float)SGN*sD.y, (float)SGN*sD.x);
    float2 u = (sub & 1) ? sB : sA;
    float2 v = (sub & 1) ? iD : sC;
    Y[q1] = (sub & 2) ? csub(u, v) : cadd(u, v);
  }
  Y[1]=cmul(Y[1],w16[0]); Y[2]=cmul(Y[2],w16[1]); Y[3]=cmul(Y[3],w16[2]);
  float2 sA=cadd(Y[0],Y[2]), sB=csub(Y[0],Y[2]), sC=cadd(Y[1],Y[3]), sD=csub(Y[1],Y[3]);
  float2 iD=make_float2(-(float)SGN*sD.y, (float)SGN*sD.x);
  X[0]=cmul(cadd(sA,sC),tw[0]); X[1]=cmul(cadd(sB,iD),tw[1]);
  X[2]=cmul(csub(sA,sC),tw[2]); X[3]=cmul(csub(sB,iD),tw[3]);
}

template<int L, int M, int SGN>
__device__ __forceinline__ void r16(const float2* src, float2* dst, int bf, int sub,
                                    const float2* w16, const float2* tw){
  const int j = bf / M, k = bf - j * M;
  const int base = k + M * j;
  float2 in[16];
  #pragma unroll
  for (int q = 0; q < 16; ++q) in[q] = src[SIG(base + 64 * q)];
  float2 X[4]; r16_core<SGN>(in, sub, w16, tw, X);
  const int obase = k + M * (16 * j + sub);
  #pragma unroll
  for (int p2 = 0; p2 < 4; ++p2) dst[SIG(obase + 4 * M * p2)] = X[p2];
}

__device__ __forceinline__ void r16_final(const float2* src, int bf, int sub,
                                          const float2* w16, float2 X[4]){
  float2 in[16];
  #pragma unroll
  for (int q = 0; q < 16; ++q) in[q] = src[SIG(bf + 64 * q)];
  float2 Y[4];
  #pragma unroll
  for (int q1 = 0; q1 < 4; ++q1){
    float2 a0=in[q1], a1=in[q1+4], a2=in[q1+8], a3=in[q1+12];
    float2 sA=cadd(a0,a2), sB=csub(a0,a2), sC=cadd(a1,a3), sD=csub(a1,a3);
    float2 iD=make_float2(-sD.y, sD.x);
    float2 u = (sub & 1) ? sB : sA;
    float2 v = (sub & 1) ? iD : sC;
    Y[q1] = (sub & 2) ? csub(u, v) : cadd(u, v);
  }
  Y[1]=cmul(Y[1],w16[0]); Y[2]=cmul(Y[2],w16[1]); Y[3]=cmul(Y[3],w16[2]);
  float2 sA=cadd(Y[0],Y[2]), sB=csub(Y[0],Y[2]), sC=cadd(Y[1],Y[3]), sD=csub(Y[1],Y[3]);
  float2 iD=make_float2(-sD.y, sD.x);
  X[0]=cadd(sA,sC); X[1]=cadd(sB,iD); X[2]=csub(sA,sC); X[3]=csub(sB,iD);
}

__device__ __forceinline__ void phaseD_core(const float2 a0[4], const float2 b0[4],
                                            int tid, const FSetup& S, float2 Xo[4]){
  float2 Z1[4], Z2[4];
  dft4_full<-1>(a0, Z1);
  dft4_full<-1>(b0, Z2);
  float2 Wv[4];
  #pragma unroll
  for (int q = 0; q < 4; ++q){
    float2 zk = Z1[q];
    float2 zp = Z2[3 - q];
    if (tid == 0) zp = Z2[(4 - q) & 3];
    float2 E = make_float2(0.5f*(zk.x+zp.x),  0.5f*(zk.y-zp.y));
    float2 O = make_float2(0.5f*(zk.y+zp.y), -0.5f*(zk.x-zp.x));
    float2 w = S.wmd[q];
    float2 wO = cmul(w, O);
    float2 Hk  = cadd(E, wO), Hk2 = csub(E, wO);
    float2 Yk  = cmul(Hk,  S.lamA[q]);
    float2 Yk2 = cmul(Hk2, S.lamB[q]);
    float2 Sm = cadd(Yk, Yk2), Dd = csub(Yk, Yk2);
    float2 cw = make_float2(w.x, -w.y);
    float2 cd = cmul(cw, Dd);
    Wv[q] = make_float2(Sm.x - cd.y, Sm.y + cd.x);
  }
  float2 X[4]; dft4_full<1>(Wv, X);
  #pragma unroll
  for (int p = 0; p < 4; ++p) Xo[p] = cmul(X[p], S.twD[p]);
}

__device__ __forceinline__ void phaseD(const float2* src, float2* dst, int tid, const FSetup& S){
  const int k2 = (256 - tid) & 255;
  float2 a0[4], b0[4];
  #pragma unroll
  for (int q = 0; q < 4; ++q){
    a0[q] = src[SIG(tid + 256*q)];
    b0[q] = src[SIG(k2  + 256*q)];
  }
  float2 X[4]; phaseD_core(a0, b0, tid, S, X);
  #pragma unroll
  for (int p = 0; p < 4; ++p) dst[SIG(4*tid + p)] = X[p];
}

__device__ __forceinline__ void fft5_phases(float2* hz, float2* bA, float2* bB,
                                            int tid, const FSetup& S){
  const int bf = tid >> 2, sub = tid & 3;
  r16<64,  1, -1>(hz, bA, bf, sub, S.w16f, S.twA); __syncthreads();
  r16< 4, 16, -1>(bA, bB, bf, sub, S.w16f, S.twB); __syncthreads();
  phaseD(bB, bA, tid, S);                          __syncthreads();
  r16<16,  4,  1>(bA, bB, bf, sub, S.w16i, S.twE); __syncthreads();
}

// ---------------- f32 -> bf16 bulk convert ----------------
__global__ __launch_bounds__(256) void cvt_bf16(const float* __restrict__ in,
                                                unsigned short* __restrict__ out, int n8){
  int i = blockIdx.x * 256 + threadIdx.x;
  if (i >= n8) return;
  float4 a = ((const float4*)in)[2 * i];
  float4 b = ((const float4*)in)[2 * i + 1];
  us8 r;
  r[0] = f2bf(a.x); r[1] = f2bf(a.y); r[2] = f2bf(a.z); r[3] = f2bf(a.w);
  r[4] = f2bf(b.x); r[5] = f2bf(b.y); r[6] = f2bf(b.z); r[7] = f2bf(b.w);
  ((us8*)out)[i] = r;
}

// ---------------- lam[k] = fft(c)[k] / 2048 ----------------
__global__ __launch_bounds__(256) void dft_c(const float* __restrict__ c, float2* __restrict__ lam){
  __shared__ float cs[2048];
  int tid = threadIdx.x;
  for (int i = tid; i < 2048; i += 256) cs[i] = c[i];
  __syncthreads();
  int k = blockIdx.x * 256 + tid;
  float sr = 0.f, si = 0.f;
  for (int j = 0; j < 2048; ++j){
    int ph = (j * k) & 2047;
    float sn, co; sincos2pi((float)ph * (1.0f / 2048.0f), sn, co);
    float cv = cs[j];
    sr = __fmaf_rn(cv,  co, sr);
    si = __fmaf_rn(-cv, sn, si);
  }
  lam[k] = make_float2(sr * (1.0f / 2048.0f), si * (1.0f / 2048.0f));
}

// ---------------- circ_x: pre[row] = ifft(lamx*fft(x_row)) + b ----------------
__global__ __launch_bounds__(256, 2) void circx(const float* __restrict__ x,
                                                const float* __restrict__ bias,
                                                const float2* __restrict__ lam_g,
                                                float* __restrict__ pre){
  __shared__ float2 hz[1088], bA[1088], bB[1088];
  const int tid = threadIdx.x;
  FSetup S; make_setup(S, tid, lam_g);
  const int bf = tid >> 2, sub = tid & 3;
  const int i0 = bf + 64 * sub;
  float2 bv[4];
  #pragma unroll
  for (int p2 = 0; p2 < 4; ++p2) bv[p2] = ((const float2*)bias)[i0 + 256*p2];
  for (int r = 0; r < 8; ++r){
    const size_t row = (size_t)blockIdx.x * 8 + r;
    const float2* xr = (const float2*)(x + row * 2048);
    for (int i = tid; i < 1024; i += 256) hz[SIG(i)] = xr[i];
    __syncthreads();
    fft5_phases(hz, bA, bB, tid, S);
    float2 X[4]; r16_final(bB, bf, sub, S.w16i, X);
    float2* prow = (float2*)(pre + row * 2048);
    #pragma unroll
    for (int p2 = 0; p2 < 4; ++p2){
      int n = i0 + 256*p2;
      prow[n] = make_float2(X[p2].x + bv[p2].x, X[p2].y + bv[p2].y);
    }
    __syncthreads();
  }
}

// ---------------- gate GEMM: g = silu(xb @ Wb^T + bg) -> h rows 1..T ----------------
__global__ __launch_bounds__(256) void gemm_gate(const unsigned short* __restrict__ A,
                                                 const unsigned short* __restrict__ B,
                                                 const float* __restrict__ bg,
                                                 float* __restrict__ houtp){
  __shared__ unsigned short As[128 * 32];
  __shared__ unsigned short Bs[128 * 32];
  const int tid  = threadIdx.x;
  const int lane = tid & 63;
  const int wave = tid >> 6;
  const int wr = wave >> 1, wc = wave & 1;
  const int m0 = blockIdx.x * 128, n0 = blockIdx.y * 128;

  const int srow = tid >> 1;
  const int scol = (tid & 1) << 4;
  const unsigned short* ga = A + (size_t)(m0 + srow) * 2048 + scol;
  const unsigned short* gb = B + (size_t)(n0 + srow) * 2048 + scol;
  unsigned short* la = As + srow * 32 + scol;
  unsigned short* lb = Bs + srow * 32 + scol;

  f32x4 acc[4][4];
  #pragma unroll
  for (int m = 0; m < 4; ++m)
    #pragma unroll
    for (int n = 0; n < 4; ++n)
      acc[m][n] = f32x4{0.f, 0.f, 0.f, 0.f};

  const int arow = wr * 64 + (lane & 15);
  const int brow = wc * 64 + (lane & 15);
  const int koff = (lane >> 4) * 8;

  for (int ks = 0; ks < 64; ++ks){
    const int k0 = ks * 32;
    us8 va0 = *(const us8*)(ga + k0);
    us8 va1 = *(const us8*)(ga + k0 + 8);
    us8 vb0 = *(const us8*)(gb + k0);
    us8 vb1 = *(const us8*)(gb + k0 + 8);
    __syncthreads();
    *(us8*)(la)     = va0; *(us8*)(la + 8) = va1;
    *(us8*)(lb)     = vb0; *(us8*)(lb + 8) = vb1;
    __syncthreads();
    bf16x8 av[4], bv[4];
    #pragma unroll
    for (int m = 0; m < 4; ++m) av[m] = *(const bf16x8*)(As + (arow + m * 16) * 32 + koff);
    #pragma unroll
    for (int n = 0; n < 4; ++n) bv[n] = *(const bf16x8*)(Bs + (brow + n * 16) * 32 + koff);
    #pragma unroll
    for (int m = 0; m < 4; ++m)
      #pragma unroll
      for (int n = 0; n < 4; ++n)
        acc[m][n] = __builtin_amdgcn_mfma_f32_16x16x32_bf16(av[m], bv[n], acc[m][n], 0, 0, 0);
  }
  #pragma unroll
  for (int n = 0; n < 4; ++n){
    const int ng = n0 + wc * 64 + n * 16 + (lane & 15);
    const float bgv = bg[ng];
    #pragma unroll
    for (int m = 0; m < 4; ++m){
      const int mbase = m0 + wr * 64 + m * 16 + (lane >> 4) * 4;
      #pragma unroll
      for (int r = 0; r < 4; ++r){
        float v = acc[m][n][r] + bgv;
        float s = v / (1.0f + __expf(-v));
        houtp[(size_t)(mbase + r + 16) * 2048 + ng] = s;
      }
    }
  }
}

extern "C" void kernel_launch(void* const* d_in, const int* in_sizes, int n_in,
                              void* d_out, int out_size, void* d_ws, size_t ws_size,
                              hipStream_t stream){
  const float* x  = (const float*)d_in[0];
  const float* h0 = (const float*)d_in[1];
  const float* ch = (const float*)d_in[2];
  const float* cx = (const float*)d_in[3];
  const float* Wg = (const float*)d_in[4];
  const float* bb = (const float*)d_in[5];
  const float* bg = (const float*)d_in[6];
  float* outp  = (float*)d_out;                        // [T,B,D]
  float* houtp = outp + (size_t)1024 * 16 * 2048;      // [T+1,B,D]

  char* w = (char*)d_ws;
  unsigned short* xb = (unsigned short*)w; w += (size_t)16384 * 2048 * 2;
  unsigned short* Wb = (unsigned short*)w; w += (size_t)2048 * 2048 * 2;
  float2* lamh = (float2*)w; w += 2048 * sizeof(float2);
  float2* lamx = (float2*)w; w += 2048 * sizeof(float2);

  cvt_bf16 <<<dim3(16384), dim3(256), 0, stream>>>(x,  xb, 16384 * 2048 / 8);
  cvt_bf16 <<<dim3(2048),  dim3(256), 0, stream>>>(Wg, Wb,  2048 * 2048 / 8);
  dft_c    <<<dim3(8),     dim3(256), 0, stream>>>(ch, lamh);
  dft_c    <<<dim3(8),     dim3(256), 0, stream>>>(cx, lamx);
  circx    <<<dim3(2048),  dim3(256), 0, stream>>>(x, bb, lamx, outp);       // pre -> outp
  gemm_gate<<<dim3(128,16),dim3(256), 0, stream>>>(xb, Wb, bg, houtp);       // g -> h rows 1..T
  recur_q  <<<dim3(16),    dim3(256), 0, stream>>>(h0, lamh, outp, houtp);
}

// Round 5
// 2621.198 us; speedup vs baseline: 2.9206x; 1.3136x over previous
//
#include <hip/hip_runtime.h>
#include <hip/hip_bf16.h>

// CirculantElmanCell: T=1024, B=16, D=2048
// out0: output [T,B,D] f32 ; out1: h [T+1,B,D] f32 (concatenated in d_out)

typedef __attribute__((ext_vector_type(8))) unsigned short us8;
typedef __attribute__((ext_vector_type(8))) __bf16 bf16x8;
typedef __attribute__((ext_vector_type(4))) float f32x4;

__device__ __forceinline__ int SIG(int i){ return i + (i >> 4); }  // circx swizzle (legacy, verified)
// recur swizzle: fold high bits into bank bits; bijective on [0,1024)
__device__ __forceinline__ int SIGF(int a){ return a ^ (((a >> 8) & 3) << 2) ^ ((a >> 6) & 3); }
__device__ __forceinline__ int rev2i(int v){ return ((v & 1) << 1) | ((v >> 1) & 1); }
// full DIF output permutation (involution): digits reversed + per-digit bitrev
__device__ __forceinline__ int PERMF(int i){
  return rev2i((i >> 8) & 3) | (rev2i((i >> 6) & 3) << 2) | (rev2i((i >> 4) & 3) << 4)
       | (rev2i((i >> 2) & 3) << 6) | (rev2i(i & 3) << 8);
}

// LDS-only barrier: no vmcnt drain (global loads/stores stay in flight)
#define LDSBAR() do { \
  asm volatile("s_waitcnt lgkmcnt(0)\n\ts_barrier" ::: "memory"); \
  __builtin_amdgcn_sched_barrier(0); \
} while (0)

__device__ __forceinline__ unsigned short f2bf(float f){
  unsigned int u = __float_as_uint(f);
  return (unsigned short)((u + 0x7FFFu + ((u >> 16) & 1u)) >> 16);
}

__device__ __forceinline__ void sincos2pi(float fr, float& sn, float& co){
#if __has_builtin(__builtin_amdgcn_sinf) && __has_builtin(__builtin_amdgcn_cosf)
  sn = __builtin_amdgcn_sinf(fr);   // v_sin_f32: revolutions
  co = __builtin_amdgcn_cosf(fr);
#else
  __sincosf(fr * 6.28318530717958647692f, &sn, &co);
#endif
}

__device__ __forceinline__ float2 cmul(float2 a, float2 b){
  return make_float2(a.x*b.x - a.y*b.y, a.x*b.y + a.y*b.x);
}
__device__ __forceinline__ float2 cmulc(float2 a, float2 b){   // a * conj(b)
  return make_float2(a.x*b.x + a.y*b.y, a.y*b.x - a.x*b.y);
}
__device__ __forceinline__ float2 cadd(float2 a, float2 b){ return make_float2(a.x+b.x, a.y+b.y); }
__device__ __forceinline__ float2 csub(float2 a, float2 b){ return make_float2(a.x-b.x, a.y-b.y); }

__device__ __forceinline__ float tanh_fast(float x){
  float e = __expf(2.0f * x);
  return 1.0f - 2.0f / (e + 1.0f);
}

__device__ __forceinline__ float2 wn(int num, float dinv, int sgn){
  float sn, co; sincos2pi((float)num * dinv, sn, co);
  return make_float2(co, sgn > 0 ? sn : -sn);
}

template<int SGN>
__device__ __forceinline__ void dft4_full(const float2 a[4], float2 X[4]){
  float2 sA = cadd(a[0],a[2]), sB = csub(a[0],a[2]);
  float2 sC = cadd(a[1],a[3]), sD = csub(a[1],a[3]);
  float2 iD = make_float2(-(float)SGN*sD.y, (float)SGN*sD.x);
  X[0]=cadd(sA,sC); X[1]=cadd(sB,iD); X[2]=csub(sA,sC); X[3]=csub(sB,iD);
}

// ---------------- cross-lane exchange primitives ----------------
template<int CTRL>
__device__ __forceinline__ float2 dpp2(float2 v){
  float2 r;
  r.x = __int_as_float(__builtin_amdgcn_mov_dpp(__float_as_int(v.x), CTRL, 0xF, 0xF, true));
  r.y = __int_as_float(__builtin_amdgcn_mov_dpp(__float_as_int(v.y), CTRL, 0xF, 0xF, true));
  return r;
}
template<int IMM>
__device__ __forceinline__ float2 swz2(float2 v){
  float2 r;
  r.x = __int_as_float(__builtin_amdgcn_ds_swizzle(__float_as_int(v.x), IMM));
  r.y = __int_as_float(__builtin_amdgcn_ds_swizzle(__float_as_int(v.y), IMM));
  return r;
}
__device__ __forceinline__ float2 bperm2(int addr, float2 v){
  float2 r;
  r.x = __int_as_float(__builtin_amdgcn_ds_bpermute(addr, __float_as_int(v.x)));
  r.y = __int_as_float(__builtin_amdgcn_ds_bpermute(addr, __float_as_int(v.y)));
  return r;
}
#define DPP_XOR1 0xB1  // quad_perm [1,0,3,2]
#define DPP_XOR2 0x4E  // quad_perm [2,3,0,1]

// =====================================================================
// recur_dif: 1024 threads, 1 complex point/thread, in-place radix-4 chain
// =====================================================================

// LDS-direct radix-4 stage: own output p = rev2(position digit), + twiddle
template<int POS>  // POS=0: SGN=-1 (fwd), POS=1: SGN=+1 (inv, twiddle conjugated)
__device__ __forceinline__ float2 lds4(const float2* buf, int a0, int a1, int a2, int a3,
                                       float sB, float sD, bool sel, float2 tw){
  float2 in0 = buf[a0], in1 = buf[a1], in2 = buf[a2], in3 = buf[a3];
  float2 u = make_float2(fmaf(sB, in2.x, in0.x), fmaf(sB, in2.y, in0.y));
  float2 v = make_float2(fmaf(sB, in3.x, in1.x), fmaf(sB, in3.y, in1.y));
  float2 iv = POS ? make_float2(-v.y, v.x) : make_float2(v.y, -v.x);
  float2 se = sel ? iv : v;
  float2 X = make_float2(fmaf(sD, se.x, u.x), fmaf(sD, se.y, u.y));
  return POS ? cmulc(X, tw) : cmul(X, tw);
}

// round 2 of a cross-lane radix-4 butterfly: X = v_keep + sgn0 * rot(v_rot)
template<int POS>
__device__ __forceinline__ float2 round2f(float2 own, float2 par, bool c0, bool c1, float sgn0){
  float2 vk = c0 ? par : own;
  float2 vr = c0 ? own : par;
  float2 vrr = POS ? make_float2(-vr.y, vr.x) : make_float2(vr.y, -vr.x);
  float2 rot = c1 ? vrr : vr;
  return make_float2(fmaf(sgn0, rot.x, vk.x), fmaf(sgn0, rot.y, vk.y));
}

// three cross-lane stages: d=16 (bits 4-5), d=4 (bits 2-3), d=1 (bits 0-1)
template<int POS>
__device__ __forceinline__ float2 lanes3(float2 T, int bpa,
    float sH2, bool c02, bool c12, float sL2, float2 tw2,
    float sH3, bool c03, bool c13, float sL3, float2 tw3,
    float sH4, bool c04, bool c14, float sL4){
  { // d=16: round1 lane^32 (bpermute), round2 lane^16 (swizzle)
    float2 par = bperm2(bpa, T);
    T.x = fmaf(sH2, T.x, par.x); T.y = fmaf(sH2, T.y, par.y);
    float2 p2 = swz2<0x401F>(T);
    T = round2f<POS>(T, p2, c02, c12, sL2);
    T = POS ? cmulc(T, tw2) : cmul(T, tw2);
  }
  { // d=4: lane^8, lane^4
    float2 par = swz2<0x201F>(T);
    T.x = fmaf(sH3, T.x, par.x); T.y = fmaf(sH3, T.y, par.y);
    float2 p2 = swz2<0x101F>(T);
    T = round2f<POS>(T, p2, c03, c13, sL3);
    T = POS ? cmulc(T, tw3) : cmul(T, tw3);
  }
  { // d=1: lane^2, lane^1 (no stage twiddle, B=4, r=0)
    float2 par = dpp2<DPP_XOR2>(T);
    T.x = fmaf(sH4, T.x, par.x); T.y = fmaf(sH4, T.y, par.y);
    float2 p2 = dpp2<DPP_XOR1>(T);
    T = round2f<POS>(T, p2, c04, c14, sL4);
  }
  return T;
}

__global__ __launch_bounds__(1024, 1) void recur_dif(const float* __restrict__ h0,
                                                     const float2* __restrict__ lam_g,
                                                     float* __restrict__ outp,    // pre in, out out
                                                     float* __restrict__ houtp){  // rows 1..T: g -> h
  __shared__ float2 hz[1024], bA[1024], bB[1024];
  const int i = threadIdx.x;           // point index 0..1023
  const int b = blockIdx.x;
  const int lane = i & 63;

  // ---- per-thread constants (all t-invariant) ----
  const int p0 = rev2i((i >> 8) & 3);
  const int p1 = rev2i((i >> 6) & 3);
  const int p2v = rev2i((i >> 4) & 3);
  const int p3v = rev2i((i >> 2) & 3);
  const float2 tw0 = wn(((i & 255) * p0) & 1023, 1.0f/1024.0f, -1);
  const float2 tw1 = wn(((i & 63) * p1) & 255, 1.0f/256.0f, -1);
  const float2 tw2 = wn(((i & 15) * p2v) & 63, 1.0f/64.0f, -1);
  const float2 tw3 = wn(((i & 3) * p3v) & 15, 1.0f/16.0f, -1);
  const float2 wmd = wn(i & 2047, 1.0f/2048.0f, -1);
  const float2 lamA = lam_g[i];
  const float2 lamB = lam_g[i + 1024];
  const float sB0 = (p0 & 1) ? -1.f : 1.f, sD0 = (p0 & 2) ? -1.f : 1.f; const bool sel0 = p0 & 1;
  const float sB1 = (p1 & 1) ? -1.f : 1.f, sD1 = (p1 & 2) ? -1.f : 1.f; const bool sel1 = p1 & 1;
  const bool c02 = (i >> 4) & 1, c12 = (i >> 5) & 1;
  const bool c03 = (i >> 2) & 1, c13 = (i >> 3) & 1;
  const bool c04 = i & 1,        c14 = (i >> 1) & 1;
  const float sH2 = c12 ? -1.f : 1.f, sL2 = c02 ? -1.f : 1.f;
  const float sH3 = c13 ? -1.f : 1.f, sL3 = c03 ? -1.f : 1.f;
  const float sH4 = c14 ? -1.f : 1.f, sL4 = c04 ? -1.f : 1.f;
  // addresses
  const int sfi  = SIGF(i);
  const int swP  = SIGF(PERMF(i));
  const int smir = SIGF((1024 - i) & 1023);
  const int bpa  = (lane ^ 32) << 2;
  const int r256 = i & 255;
  const int aA0 = SIGF(r256), aA1 = SIGF(r256 + 256), aA2 = SIGF(r256 + 512), aA3 = SIGF(r256 + 768);
  const int b64 = (i & ~255) + (i & 63);
  const int aB0 = SIGF(b64), aB1 = SIGF(b64 + 64), aB2 = SIGF(b64 + 128), aB3 = SIGF(b64 + 192);

  // ---- init: h0 -> hz (swizzled) and h row 0 (linear) ----
  {
    const float2* h02 = (const float2*)(h0 + (size_t)b * 2048);
    float2* hrow0 = (float2*)(houtp + (size_t)b * 2048);
    float2 v = h02[i];
    hz[sfi] = v;
    hrow0[i] = v;
  }
  __syncthreads();

  #pragma unroll 1
  for (int t = 0; t < 1024; ++t){
    float* orow = outp  + ((size_t)t * 16 + b) * 2048;
    float* hrow = houtp + ((size_t)(t + 1) * 16 + b) * 2048;
    float2 pr = *(const float2*)(orow + 2 * i);   // pre (circ_x + b)
    float2 gv = *(const float2*)(hrow + 2 * i);   // gate (silu)

    // P1: fwd d=256
    float2 T = lds4<0>(hz, aA0, aA1, aA2, aA3, sB0, sD0, sel0, tw0);
    bA[sfi] = T;
    LDSBAR();
    // P2: fwd d=64 + lane stages d=16,4,1  -> Z at position i = Z[PERM(i)]
    T = lds4<0>(bA, aB0, aB1, aB2, aB3, sB1, sD1, sel1, tw1);
    T = lanes3<0>(T, bpa, sH2, c02, c12, sL2, tw2, sH3, c03, c13, sL3, tw3, sH4, c04, c14, sL4);
    bB[swP] = T;                                   // un-permute: addr holds Z[natural]
    LDSBAR();
    // P3: Hermitian unpack * lam * repack at natural k = i (verified formula)
    {
      float2 zk = bB[sfi];
      float2 zp = bB[smir];
      float2 E = make_float2(0.5f*(zk.x+zp.x),  0.5f*(zk.y-zp.y));
      float2 O = make_float2(0.5f*(zk.y+zp.y), -0.5f*(zk.x-zp.x));
      float2 wO = cmul(wmd, O);
      float2 Hk  = cadd(E, wO), Hk2 = csub(E, wO);
      float2 Yk  = cmul(Hk,  lamA);
      float2 Yk2 = cmul(Hk2, lamB);
      float2 Sm = cadd(Yk, Yk2), Dd = csub(Yk, Yk2);
      float2 cw = make_float2(wmd.x, -wmd.y);
      float2 cd = cmul(cw, Dd);
      bA[sfi] = make_float2(Sm.x - cd.y, Sm.y + cd.x);   // W[i] natural
    }
    LDSBAR();
    // P4: inv d=256
    T = lds4<1>(bA, aA0, aA1, aA2, aA3, sB0, sD0, sel0, tw0);
    bB[sfi] = T;
    LDSBAR();
    // P5: inv d=64 + lane stages -> y at position i = y[PERM(i)]
    T = lds4<1>(bB, aB0, aB1, aB2, aB3, sB1, sD1, sel1, tw1);
    T = lanes3<1>(T, bpa, sH2, c02, c12, sL2, tw2, sH3, c03, c13, sL3, tw3, sH4, c04, c14, sL4);
    bA[swP] = T;                                   // re-permute: addr holds y[natural]
    LDSBAR();
    // P6: epilogue at natural i
    {
      float2 y = bA[sfi];
      float hx = tanh_fast(y.x + pr.x);
      float hy = tanh_fast(y.y + pr.y);
      float ox = hx * gv.x, oy = hy * gv.y;
      // tie h to gv: hrow store (same addr as gv load) must not pass the load
      asm volatile("" : "+v"(hx), "+v"(hy) : "v"(gv.x), "v"(gv.y));
      float2 hv = make_float2(hx, hy);
      hz[sfi] = hv;
      *(float2*)(hrow + 2 * i) = hv;
      *(float2*)(orow + 2 * i) = make_float2(ox, oy);
    }
    LDSBAR();
  }
}

// =====================================================================
// circx path (unchanged, verified)
// =====================================================================
struct FSetup {
  float2 w16f[3], w16i[3];
  float2 twA[4], twB[4], twD[4], twE[4];
  float2 wmd[4];
  float2 lamA[4], lamB[4];
};

__device__ __forceinline__ void make_setup(FSetup& S, int tid, const float2* __restrict__ lam_g){
  const int sub = tid & 3, bf = tid >> 2;
  #pragma unroll
  for (int i = 0; i < 3; ++i){
    S.w16f[i] = wn(((i + 1) * sub) & 15, 1.0f/16.0f, -1);
    S.w16i[i] = make_float2(S.w16f[i].x, -S.w16f[i].y);
  }
  #pragma unroll
  for (int p2 = 0; p2 < 4; ++p2){
    S.twA[p2] = wn((bf * (sub + 4*p2)) & 1023, 1.0f/1024.0f, -1);
    S.twB[p2] = wn((16 * (bf >> 4) * (sub + 4*p2)) & 1023, 1.0f/1024.0f, -1);
    S.twD[p2] = wn((tid * p2) & 1023, 1.0f/1024.0f, +1);
    S.twE[p2] = wn((4 * (bf >> 2) * (sub + 4*p2)) & 1023, 1.0f/1024.0f, +1);
  }
  #pragma unroll
  for (int q = 0; q < 4; ++q){
    int k = tid + 256 * q;
    S.wmd[q]  = wn(k & 2047, 1.0f/2048.0f, -1);
    S.lamA[q] = lam_g[k];
    S.lamB[q] = lam_g[k + 1024];
  }
}

template<int SGN>
__device__ __forceinline__ void r16_core(const float2 in[16], int sub,
                                         const float2* w16, const float2* tw, float2 X[4]){
  float2 Y[4];
  #pragma unroll
  for (int q1 = 0; q1 < 4; ++q1){
    float2 a0=in[q1], a1=in[q1+4], a2=in[q1+8], a3=in[q1+12];
    float2 sA=cadd(a0,a2), sB=csub(a0,a2), sC=cadd(a1,a3), sD=csub(a1,a3);
    float2 iD=make_float2(-(float)SGN*sD.y, (float)SGN*sD.x);
    float2 u = (sub & 1) ? sB : sA;
    float2 v = (sub & 1) ? iD : sC;
    Y[q1] = (sub & 2) ? csub(u, v) : cadd(u, v);
  }
  Y[1]=cmul(Y[1],w16[0]); Y[2]=cmul(Y[2],w16[1]); Y[3]=cmul(Y[3],w16[2]);
  float2 sA=cadd(Y[0],Y[2]), sB=csub(Y[0],Y[2]), sC=cadd(Y[1],Y[3]), sD=csub(Y[1],Y[3]);
  float2 iD=make_float2(-(float)SGN*sD.y, (float)SGN*sD.x);
  X[0]=cmul(cadd(sA,sC),tw[0]); X[1]=cmul(cadd(sB,iD),tw[1]);
  X[2]=cmul(csub(sA,sC),tw[2]); X[3]=cmul(csub(sB,iD),tw[3]);
}

template<int L, int M, int SGN>
__device__ __forceinline__ void r16(const float2* src, float2* dst, int bf, int sub,
                                    const float2* w16, const float2* tw){
  const int j = bf / M, k = bf - j * M;
  const int base = k + M * j;
  float2 in[16];
  #pragma unroll
  for (int q = 0; q < 16; ++q) in[q] = src[SIG(base + 64 * q)];
  float2 X[4]; r16_core<SGN>(in, sub, w16, tw, X);
  const int obase = k + M * (16 * j + sub);
  #pragma unroll
  for (int p2 = 0; p2 < 4; ++p2) dst[SIG(obase + 4 * M * p2)] = X[p2];
}

__device__ __forceinline__ void r16_final(const float2* src, int bf, int sub,
                                          const float2* w16, float2 X[4]){
  float2 in[16];
  #pragma unroll
  for (int q = 0; q < 16; ++q) in[q] = src[SIG(bf + 64 * q)];
  float2 Y[4];
  #pragma unroll
  for (int q1 = 0; q1 < 4; ++q1){
    float2 a0=in[q1], a1=in[q1+4], a2=in[q1+8], a3=in[q1+12];
    float2 sA=cadd(a0,a2), sB=csub(a0,a2), sC=cadd(a1,a3), sD=csub(a1,a3);
    float2 iD=make_float2(-sD.y, sD.x);
    float2 u = (sub & 1) ? sB : sA;
    float2 v = (sub & 1) ? iD : sC;
    Y[q1] = (sub & 2) ? csub(u, v) : cadd(u, v);
  }
  Y[1]=cmul(Y[1],w16[0]); Y[2]=cmul(Y[2],w16[1]); Y[3]=cmul(Y[3],w16[2]);
  float2 sA=cadd(Y[0],Y[2]), sB=csub(Y[0],Y[2]), sC=cadd(Y[1],Y[3]), sD=csub(Y[1],Y[3]);
  float2 iD=make_float2(-sD.y, sD.x);
  X[0]=cadd(sA,sC); X[1]=cadd(sB,iD); X[2]=csub(sA,sC); X[3]=csub(sB,iD);
}

__device__ __forceinline__ void phaseD_core(const float2 a0[4], const float2 b0[4],
                                            int tid, const FSetup& S, float2 Xo[4]){
  float2 Z1[4], Z2[4];
  dft4_full<-1>(a0, Z1);
  dft4_full<-1>(b0, Z2);
  float2 Wv[4];
  #pragma unroll
  for (int q = 0; q < 4; ++q){
    float2 zk = Z1[q];
    float2 zp = Z2[3 - q];
    if (tid == 0) zp = Z2[(4 - q) & 3];
    float2 E = make_float2(0.5f*(zk.x+zp.x),  0.5f*(zk.y-zp.y));
    float2 O = make_float2(0.5f*(zk.y+zp.y), -0.5f*(zk.x-zp.x));
    float2 w = S.wmd[q];
    float2 wO = cmul(w, O);
    float2 Hk  = cadd(E, wO), Hk2 = csub(E, wO);
    float2 Yk  = cmul(Hk,  S.lamA[q]);
    float2 Yk2 = cmul(Hk2, S.lamB[q]);
    float2 Sm = cadd(Yk, Yk2), Dd = csub(Yk, Yk2);
    float2 cw = make_float2(w.x, -w.y);
    float2 cd = cmul(cw, Dd);
    Wv[q] = make_float2(Sm.x - cd.y, Sm.y + cd.x);
  }
  float2 X[4]; dft4_full<1>(Wv, X);
  #pragma unroll
  for (int p = 0; p < 4; ++p) Xo[p] = cmul(X[p], S.twD[p]);
}

__device__ __forceinline__ void phaseD(const float2* src, float2* dst, int tid, const FSetup& S){
  const int k2 = (256 - tid) & 255;
  float2 a0[4], b0[4];
  #pragma unroll
  for (int q = 0; q < 4; ++q){
    a0[q] = src[SIG(tid + 256*q)];
    b0[q] = src[SIG(k2  + 256*q)];
  }
  float2 X[4]; phaseD_core(a0, b0, tid, S, X);
  #pragma unroll
  for (int p = 0; p < 4; ++p) dst[SIG(4*tid + p)] = X[p];
}

__device__ __forceinline__ void fft5_phases(float2* hz, float2* bA, float2* bB,
                                            int tid, const FSetup& S){
  const int bf = tid >> 2, sub = tid & 3;
  r16<64,  1, -1>(hz, bA, bf, sub, S.w16f, S.twA); __syncthreads();
  r16< 4, 16, -1>(bA, bB, bf, sub, S.w16f, S.twB); __syncthreads();
  phaseD(bB, bA, tid, S);                          __syncthreads();
  r16<16,  4,  1>(bA, bB, bf, sub, S.w16i, S.twE); __syncthreads();
}

// ---------------- f32 -> bf16 bulk convert ----------------
__global__ __launch_bounds__(256) void cvt_bf16(const float* __restrict__ in,
                                                unsigned short* __restrict__ out, int n8){
  int i = blockIdx.x * 256 + threadIdx.x;
  if (i >= n8) return;
  float4 a = ((const float4*)in)[2 * i];
  float4 b = ((const float4*)in)[2 * i + 1];
  us8 r;
  r[0] = f2bf(a.x); r[1] = f2bf(a.y); r[2] = f2bf(a.z); r[3] = f2bf(a.w);
  r[4] = f2bf(b.x); r[5] = f2bf(b.y); r[6] = f2bf(b.z); r[7] = f2bf(b.w);
  ((us8*)out)[i] = r;
}

// ---------------- lam[k] = fft(c)[k] / 2048 ----------------
__global__ __launch_bounds__(256) void dft_c(const float* __restrict__ c, float2* __restrict__ lam){
  __shared__ float cs[2048];
  int tid = threadIdx.x;
  for (int i = tid; i < 2048; i += 256) cs[i] = c[i];
  __syncthreads();
  int k = blockIdx.x * 256 + tid;
  float sr = 0.f, si = 0.f;
  for (int j = 0; j < 2048; ++j){
    int ph = (j * k) & 2047;
    float sn, co; sincos2pi((float)ph * (1.0f / 2048.0f), sn, co);
    float cv = cs[j];
    sr = __fmaf_rn(cv,  co, sr);
    si = __fmaf_rn(-cv, sn, si);
  }
  lam[k] = make_float2(sr * (1.0f / 2048.0f), si * (1.0f / 2048.0f));
}

// ---------------- circ_x: pre[row] = ifft(lamx*fft(x_row)) + b ----------------
__global__ __launch_bounds__(256, 2) void circx(const float* __restrict__ x,
                                                const float* __restrict__ bias,
                                                const float2* __restrict__ lam_g,
                                                float* __restrict__ pre){
  __shared__ float2 hz[1088], bA[1088], bB[1088];
  const int tid = threadIdx.x;
  FSetup S; make_setup(S, tid, lam_g);
  const int bf = tid >> 2, sub = tid & 3;
  const int i0 = bf + 64 * sub;
  float2 bv[4];
  #pragma unroll
  for (int p2 = 0; p2 < 4; ++p2) bv[p2] = ((const float2*)bias)[i0 + 256*p2];
  for (int r = 0; r < 8; ++r){
    const size_t row = (size_t)blockIdx.x * 8 + r;
    const float2* xr = (const float2*)(x + row * 2048);
    for (int i = tid; i < 1024; i += 256) hz[SIG(i)] = xr[i];
    __syncthreads();
    fft5_phases(hz, bA, bB, tid, S);
    float2 X[4]; r16_final(bB, bf, sub, S.w16i, X);
    float2* prow = (float2*)(pre + row * 2048);
    #pragma unroll
    for (int p2 = 0; p2 < 4; ++p2){
      int n = i0 + 256*p2;
      prow[n] = make_float2(X[p2].x + bv[p2].x, X[p2].y + bv[p2].y);
    }
    __syncthreads();
  }
}

// ---------------- gate GEMM: g = silu(xb @ Wb^T + bg) -> h rows 1..T ----------------
__global__ __launch_bounds__(256) void gemm_gate(const unsigned short* __restrict__ A,
                                                 const unsigned short* __restrict__ B,
                                                 const float* __restrict__ bg,
                                                 float* __restrict__ houtp){
  __shared__ unsigned short As[128 * 32];
  __shared__ unsigned short Bs[128 * 32];
  const int tid  = threadIdx.x;
  const int lane = tid & 63;
  const int wave = tid >> 6;
  const int wr = wave >> 1, wc = wave & 1;
  const int m0 = blockIdx.x * 128, n0 = blockIdx.y * 128;

  const int srow = tid >> 1;
  const int scol = (tid & 1) << 4;
  const unsigned short* ga = A + (size_t)(m0 + srow) * 2048 + scol;
  const unsigned short* gb = B + (size_t)(n0 + srow) * 2048 + scol;
  unsigned short* la = As + srow * 32 + scol;
  unsigned short* lb = Bs + srow * 32 + scol;

  f32x4 acc[4][4];
  #pragma unroll
  for (int m = 0; m < 4; ++m)
    #pragma unroll
    for (int n = 0; n < 4; ++n)
      acc[m][n] = f32x4{0.f, 0.f, 0.f, 0.f};

  const int arow = wr * 64 + (lane & 15);
  const int brow = wc * 64 + (lane & 15);
  const int koff = (lane >> 4) * 8;

  for (int ks = 0; ks < 64; ++ks){
    const int k0 = ks * 32;
    us8 va0 = *(const us8*)(ga + k0);
    us8 va1 = *(const us8*)(ga + k0 + 8);
    us8 vb0 = *(const us8*)(gb + k0);
    us8 vb1 = *(const us8*)(gb + k0 + 8);
    __syncthreads();
    *(us8*)(la)     = va0; *(us8*)(la + 8) = va1;
    *(us8*)(lb)     = vb0; *(us8*)(lb + 8) = vb1;
    __syncthreads();
    bf16x8 av[4], bv[4];
    #pragma unroll
    for (int m = 0; m < 4; ++m) av[m] = *(const bf16x8*)(As + (arow + m * 16) * 32 + koff);
    #pragma unroll
    for (int n = 0; n < 4; ++n) bv[n] = *(const bf16x8*)(Bs + (brow + n * 16) * 32 + koff);
    #pragma unroll
    for (int m = 0; m < 4; ++m)
      #pragma unroll
      for (int n = 0; n < 4; ++n)
        acc[m][n] = __builtin_amdgcn_mfma_f32_16x16x32_bf16(av[m], bv[n], acc[m][n], 0, 0, 0);
  }
  #pragma unroll
  for (int n = 0; n < 4; ++n){
    const int ng = n0 + wc * 64 + n * 16 + (lane & 15);
    const float bgv = bg[ng];
    #pragma unroll
    for (int m = 0; m < 4; ++m){
      const int mbase = m0 + wr * 64 + m * 16 + (lane >> 4) * 4;
      #pragma unroll
      for (int r = 0; r < 4; ++r){
        float v = acc[m][n][r] + bgv;
        float s = v / (1.0f + __expf(-v));
        houtp[(size_t)(mbase + r + 16) * 2048 + ng] = s;
      }
    }
  }
}

extern "C" void kernel_launch(void* const* d_in, const int* in_sizes, int n_in,
                              void* d_out, int out_size, void* d_ws, size_t ws_size,
                              hipStream_t stream){
  const float* x  = (const float*)d_in[0];
  const float* h0 = (const float*)d_in[1];
  const float* ch = (const float*)d_in[2];
  const float* cx = (const float*)d_in[3];
  const float* Wg = (const float*)d_in[4];
  const float* bb = (const float*)d_in[5];
  const float* bg = (const float*)d_in[6];
  float* outp  = (float*)d_out;                        // [T,B,D]
  float* houtp = outp + (size_t)1024 * 16 * 2048;      // [T+1,B,D]

  char* w = (char*)d_ws;
  unsigned short* xb = (unsigned short*)w; w += (size_t)16384 * 2048 * 2;
  unsigned short* Wb = (unsigned short*)w; w += (size_t)2048 * 2048 * 2;
  float2* lamh = (float2*)w; w += 2048 * sizeof(float2);
  float2* lamx = (float2*)w; w += 2048 * sizeof(float2);

  cvt_bf16 <<<dim3(16384), dim3(256), 0, stream>>>(x,  xb, 16384 * 2048 / 8);
  cvt_bf16 <<<dim3(2048),  dim3(256), 0, stream>>>(Wg, Wb,  2048 * 2048 / 8);
  dft_c    <<<dim3(8),     dim3(256), 0, stream>>>(ch, lamh);
  dft_c    <<<dim3(8),     dim3(256), 0, stream>>>(cx, lamx);
  circx    <<<dim3(2048),  dim3(256), 0, stream>>>(x, bb, lamx, outp);       // pre -> outp
  gemm_gate<<<dim3(128,16),dim3(256), 0, stream>>>(xb, Wb, bg, houtp);       // g -> h rows 1..T
  recur_dif<<<dim3(16),    dim3(1024), 0, stream>>>(h0, lamh, outp, houtp);
}